// Round 8
// baseline (475.557 us; speedup 1.0000x reference)
//
#include <hip/hip_runtime.h>
#include <hip/hip_bf16.h>

typedef __attribute__((ext_vector_type(8))) short short8;
typedef __attribute__((ext_vector_type(4))) float floatx4;
typedef unsigned int u32;

__device__ __forceinline__ float bf2f(u32 u) {
    union { u32 u; float f; } c; c.u = u << 16; return c.f;
}
__device__ __forceinline__ float bf2f_hi(u32 u) {
    union { u32 u; float f; } c; c.u = u & 0xFFFF0000u; return c.f;
}
__device__ __forceinline__ u32 f2bf(float f) {
    union { float f; u32 u; } c; c.f = f;
    return (c.u + 0x7FFFu + ((c.u >> 16) & 1u)) >> 16;  // RNE
}
__device__ __forceinline__ short8 cvt8(const float* p) {
    float4 f0 = ((const float4*)p)[0];
    float4 f1 = ((const float4*)p)[1];
    short8 r;
    r[0] = (short)f2bf(f0.x); r[1] = (short)f2bf(f0.y);
    r[2] = (short)f2bf(f0.z); r[3] = (short)f2bf(f0.w);
    r[4] = (short)f2bf(f1.x); r[5] = (short)f2bf(f1.y);
    r[6] = (short)f2bf(f1.z); r[7] = (short)f2bf(f1.w);
    return r;
}

// gather + accumulate one node's neighborhood; lane holds feats {2*lane,2*lane+1}
__device__ __forceinline__ void gather_row(const u32* __restrict__ hw,
                                           const int* __restrict__ col,
                                           int beg, int end, int lane,
                                           float& a0, float& a1) {
    for (int c = beg; c < end; c += 64) {
        int idx = c + lane;
        int sv = (idx < end) ? col[idx] : 0;
        int m = end - c;
        if (m > 64) m = 64;
        int e = 0;
        for (; e + 16 <= m; e += 16) {
            u32 v[16];
#pragma unroll
            for (int j = 0; j < 16; ++j) {
                int s = __builtin_amdgcn_readlane(sv, e + j);
                v[j] = hw[(size_t)s * 64 + lane];
            }
#pragma unroll
            for (int j = 0; j < 16; ++j) {
                a0 += bf2f(v[j] & 0xffff);
                a1 += bf2f_hi(v[j]);
            }
        }
        for (; e + 4 <= m; e += 4) {
            u32 v[4];
#pragma unroll
            for (int j = 0; j < 4; ++j) {
                int s = __builtin_amdgcn_readlane(sv, e + j);
                v[j] = hw[(size_t)s * 64 + lane];
            }
#pragma unroll
            for (int j = 0; j < 4; ++j) {
                a0 += bf2f(v[j] & 0xffff);
                a1 += bf2f_hi(v[j]);
            }
        }
        for (; e < m; ++e) {
            int s = __builtin_amdgcn_readlane(sv, e);
            u32 v = hw[(size_t)s * 64 + lane];
            a0 += bf2f(v & 0xffff);
            a1 += bf2f_hi(v);
        }
    }
}

// ---------------- CSR build ----------------
__global__ __launch_bounds__(256) void hist_trans_k(
        const int* __restrict__ dst, int* __restrict__ bcnt, int E, int histB,
        const float* __restrict__ W1, const float* __restrict__ W2,
        const float* __restrict__ W3, const float* __restrict__ Wp1,
        const float* __restrict__ Wp2,
        unsigned short* __restrict__ o1, unsigned short* __restrict__ o2,
        unsigned short* __restrict__ o3, unsigned short* __restrict__ o4,
        unsigned short* __restrict__ o5) {
    int t = threadIdx.x;
    if ((int)blockIdx.x < histB) {
        __shared__ int h[512];
        h[t] = 0; h[t + 256] = 0;
        __syncthreads();
        int e0 = blockIdx.x * 4096;
        int ne = min(4096, E - e0);
        for (int i = t; i < ne; i += 256) atomicAdd(&h[dst[e0 + i] >> 8], 1);
        __syncthreads();
        int c = h[t];
        if (c) atomicAdd(&bcnt[t], c);
        c = h[t + 256];
        if (c) atomicAdd(&bcnt[t + 256], c);
    } else {
        int i = (blockIdx.x - histB) * 256 + t;
        const float* in; unsigned short* out; int cols, li;
        if (i < 16384)      { in = W1;  out = o1; cols = 128; li = i; }
        else if (i < 32768) { in = W2;  out = o2; cols = 128; li = i - 16384; }
        else if (i < 49152) { in = W3;  out = o3; cols = 128; li = i - 32768; }
        else if (i < 65536) { in = Wp1; out = o4; cols = 128; li = i - 49152; }
        else                { in = Wp2; out = o5; cols = 64;  li = i - 65536; }
        int r = li / cols, c = li - r * cols;
        out[(size_t)c * 128 + r] = (unsigned short)f2bf(in[li]);
    }
}

__global__ void bscan_k(const int* __restrict__ bcnt, int* __restrict__ bbase,
                        int* __restrict__ cursor, int nb, int E) {
    __shared__ int tmp[512];
    int t = threadIdx.x;
    int v = (t < nb) ? bcnt[t] : 0;
    tmp[t] = v;
    __syncthreads();
    for (int off = 1; off < 512; off <<= 1) {
        int a = (t >= off) ? tmp[t - off] : 0;
        __syncthreads();
        tmp[t] += a;
        __syncthreads();
    }
    if (t < nb) {
        int ex = tmp[t] - v;
        bbase[t] = ex;
        cursor[t] = ex;
    }
    if (t == 0) bbase[nb] = E;
}

__global__ __launch_bounds__(256) void bucket_k(const int* __restrict__ src,
                                                const int* __restrict__ dst,
                                                int* __restrict__ cursor,
                                                u32* __restrict__ pairs, int E, int nb) {
    __shared__ int cnt[512];
    __shared__ int gbase[512];
    __shared__ int cur[512];
    int t = threadIdx.x;
    cnt[t] = 0; cnt[t + 256] = 0;
    __syncthreads();
    int e0 = blockIdx.x * 8192;
    int ne = min(8192, E - e0);
    for (int i = t; i < ne; i += 256) atomicAdd(&cnt[dst[e0 + i] >> 8], 1);
    __syncthreads();
    for (int b = t; b < nb; b += 256) {
        int c = cnt[b];
        gbase[b] = c ? atomicAdd(&cursor[b], c) : 0;
        cur[b] = 0;
    }
    __syncthreads();
    for (int i = t; i < ne; i += 256) {
        int d = dst[e0 + i];
        int s = src[e0 + i];
        int b = d >> 8;
        int p = atomicAdd(&cur[b], 1);
        pairs[gbase[b] + p] = (u32)s | ((u32)(d & 255) << 24);
    }
}

#define LCOL_CAP 12288
__global__ __launch_bounds__(256) void build_k(const u32* __restrict__ pairs,
                                               const int* __restrict__ bbase,
                                               int* __restrict__ rowptr,
                                               float* __restrict__ dinv,
                                               int* __restrict__ col, int N, int E) {
    __shared__ int cnt[256], incl[256], cur[256];
    __shared__ int lcol[LCOL_CAP];
    int b = blockIdx.x, t = threadIdx.x;
    int base = bbase[b];
    int ecnt = bbase[b + 1] - base;
    cnt[t] = 0;
    __syncthreads();
    for (int j = t; j < ecnt; j += 256) atomicAdd(&cnt[pairs[base + j] >> 24], 1);
    __syncthreads();
    incl[t] = cnt[t];
    __syncthreads();
    for (int off = 1; off < 256; off <<= 1) {
        int a = (t >= off) ? incl[t - off] : 0;
        __syncthreads();
        incl[t] += a;
        __syncthreads();
    }
    int myc = cnt[t];
    int ex = incl[t] - myc;
    int node = b * 256 + t;
    if (node < N) {
        rowptr[node] = base + ex;
        dinv[node] = rsqrtf((float)myc + 1.0f);  // +1 self-loop
    }
    cur[t] = ex;
    if (b == 0 && t == 0) rowptr[N] = E;
    __syncthreads();
    if (ecnt <= LCOL_CAP) {
        for (int j = t; j < ecnt; j += 256) {
            u32 v = pairs[base + j];
            int r = atomicAdd(&cur[v >> 24], 1);
            lcol[r] = (int)(v & 0xFFFFFF);
        }
        __syncthreads();
        for (int j = t; j < ecnt; j += 256) col[base + j] = lcol[j];
    } else {
        for (int j = t; j < ecnt; j += 256) {
            u32 v = pairs[base + j];
            int r = atomicAdd(&cur[v >> 24], 1);
            col[base + r] = (int)(v & 0xFFFFFF);
        }
    }
}

// ---------------- GEMM (layer 1: x f32 -> hw bf16, dinv-scaled) ----------------
__global__ __launch_bounds__(256) void gemm1_k(const float* __restrict__ A,
                                               const short* __restrict__ Wt,
                                               const float* __restrict__ dinv,
                                               unsigned short* __restrict__ out, int M) {
    int wave = threadIdx.x >> 6;
    int lane = threadIdx.x & 63;
    int m0 = blockIdx.x * 64 + wave * 16;
    if (m0 >= M) return;
    int quad = lane >> 4, lr = lane & 15;
    int row = m0 + lr;
    bool wr = row < M;
    if (row >= M) row = M - 1;
    const float* Ab = A + (size_t)row * 128 + quad * 8;
    short8 b0 = cvt8(Ab), b1 = cvt8(Ab + 32), b2 = cvt8(Ab + 64), b3 = cvt8(Ab + 96);
    float di = dinv[row];
#pragma unroll
    for (int nt = 0; nt < 8; ++nt) {
        int ncol = nt * 16 + lr;
        const short8* Wp = (const short8*)(Wt + (size_t)ncol * 128 + quad * 8);
        short8 a0 = Wp[0], a1 = Wp[4], a2 = Wp[8], a3 = Wp[12];
        floatx4 acc = {0.f, 0.f, 0.f, 0.f};
        acc = __builtin_amdgcn_mfma_f32_16x16x32_bf16(a0, b0, acc, 0, 0, 0);
        acc = __builtin_amdgcn_mfma_f32_16x16x32_bf16(a1, b1, acc, 0, 0, 0);
        acc = __builtin_amdgcn_mfma_f32_16x16x32_bf16(a2, b2, acc, 0, 0, 0);
        acc = __builtin_amdgcn_mfma_f32_16x16x32_bf16(a3, b3, acc, 0, 0, 0);
        int c0 = nt * 16 + quad * 4;
        if (wr) {
            uint2 st;
            st.x = f2bf(acc[0] * di) | (f2bf(acc[1] * di) << 16);
            st.y = f2bf(acc[2] * di) | (f2bf(acc[3] * di) << 16);
            *(uint2*)(out + (size_t)(m0 + lr) * 128 + c0) = st;
        }
    }
}

// ---------------- fused conv: agg + bias + relu + LN + @Wnext*dinv ----------------
// 1024 threads = 16 waves, ONE node per wave (agg-identical gather), one barrier,
// then 8 waves x 1 col-tile MFMA tail.
__global__ __launch_bounds__(1024) void fconv_k(const u32* __restrict__ hw,
                                                const int* __restrict__ rowptr,
                                                const int* __restrict__ col,
                                                const float* __restrict__ dinv,
                                                const float* __restrict__ bias,
                                                const float* __restrict__ gam,
                                                const float* __restrict__ bet,
                                                const short* __restrict__ Wt,
                                                unsigned short* __restrict__ out, int N) {
    __shared__ unsigned short rows[16][136];
    int t = threadIdx.x, wave = t >> 6, lane = t & 63;
    int nb0 = blockIdx.x * 16;
    int node = nb0 + wave;
    float a0 = 0.f, a1 = 0.f;
    if (node < N) {
        int beg = rowptr[node], end = rowptr[node + 1];
        gather_row(hw, col, beg, end, lane, a0, a1);
        float di = dinv[node];
        u32 vs = hw[(size_t)node * 64 + lane];
        a0 = di * (a0 + bf2f(vs & 0xffff));
        a1 = di * (a1 + bf2f_hi(vs));
        a0 = fmaxf(a0 + bias[2 * lane], 0.f);
        a1 = fmaxf(a1 + bias[2 * lane + 1], 0.f);
        float s = a0 + a1, q = a0 * a0 + a1 * a1;
#pragma unroll
        for (int m = 32; m >= 1; m >>= 1) {
            s += __shfl_xor(s, m, 64);
            q += __shfl_xor(q, m, 64);
        }
        float mu = s * (1.f / 128.f);
        float var = q * (1.f / 128.f) - mu * mu;
        float rs = rsqrtf(fmaxf(var, 0.f) + 1e-5f);
        a0 = gam[2 * lane] * (a0 - mu) * rs + bet[2 * lane];
        a1 = gam[2 * lane + 1] * (a1 - mu) * rs + bet[2 * lane + 1];
    }
    ((u32*)&rows[wave][0])[lane] = f2bf(a0) | (f2bf(a1) << 16);
    __syncthreads();
    if (wave < 8) {
        int quad = lane >> 4, lr = lane & 15;
        short8 b0 = *(const short8*)&rows[lr][quad * 8];
        short8 b1 = *(const short8*)&rows[lr][32 + quad * 8];
        short8 b2 = *(const short8*)&rows[lr][64 + quad * 8];
        short8 b3 = *(const short8*)&rows[lr][96 + quad * 8];
        int onode = nb0 + lr;
        float di2 = (onode < N) ? dinv[onode] : 0.f;
        int ncol = wave * 16 + lr;
        const short8* Wp = (const short8*)(Wt + (size_t)ncol * 128 + quad * 8);
        short8 a0v = Wp[0], a1v = Wp[4], a2v = Wp[8], a3v = Wp[12];
        floatx4 acc = {0.f, 0.f, 0.f, 0.f};
        acc = __builtin_amdgcn_mfma_f32_16x16x32_bf16(a0v, b0, acc, 0, 0, 0);
        acc = __builtin_amdgcn_mfma_f32_16x16x32_bf16(a1v, b1, acc, 0, 0, 0);
        acc = __builtin_amdgcn_mfma_f32_16x16x32_bf16(a2v, b2, acc, 0, 0, 0);
        acc = __builtin_amdgcn_mfma_f32_16x16x32_bf16(a3v, b3, acc, 0, 0, 0);
        int c0 = wave * 16 + quad * 4;
        if (onode < N) {
            uint2 st;
            st.x = f2bf(acc[0] * di2) | (f2bf(acc[1] * di2) << 16);
            st.y = f2bf(acc[2] * di2) | (f2bf(acc[3] * di2) << 16);
            *(uint2*)(out + (size_t)onode * 128 + c0) = st;
        }
    }
}

// ---------------- fused head: agg + b3 + relu + @Wp1+bp1 + @Wp2+bp2 + sigmoid ----------------
// 1024 threads = 16 waves, one node per wave; two barriers; 8-wave then 4-wave tails.
__global__ __launch_bounds__(1024) void fhead_k(const u32* __restrict__ hw,
                                                const int* __restrict__ rowptr,
                                                const int* __restrict__ col,
                                                const float* __restrict__ dinv,
                                                const float* __restrict__ bias,
                                                const short* __restrict__ Wp1t,
                                                const float* __restrict__ bp1,
                                                const short* __restrict__ Wp2t,
                                                const float* __restrict__ bp2,
                                                float* __restrict__ out, int N) {
    __shared__ unsigned short rows[16][136];
    __shared__ unsigned short h1s[16][136];
    int t = threadIdx.x, wave = t >> 6, lane = t & 63;
    int nb0 = blockIdx.x * 16;
    int node = nb0 + wave;
    float a0 = 0.f, a1 = 0.f;
    if (node < N) {
        int beg = rowptr[node], end = rowptr[node + 1];
        gather_row(hw, col, beg, end, lane, a0, a1);
        float di = dinv[node];
        u32 vs = hw[(size_t)node * 64 + lane];
        a0 = di * (a0 + bf2f(vs & 0xffff));
        a1 = di * (a1 + bf2f_hi(vs));
        a0 = fmaxf(a0 + bias[2 * lane], 0.f);
        a1 = fmaxf(a1 + bias[2 * lane + 1], 0.f);
    }
    ((u32*)&rows[wave][0])[lane] = f2bf(a0) | (f2bf(a1) << 16);
    __syncthreads();
    int quad = lane >> 4, lr = lane & 15;
    if (wave < 8) {  // h1 = h @ Wp1 + bp1 (1 col-tile per wave)
        short8 b0 = *(const short8*)&rows[lr][quad * 8];
        short8 b1 = *(const short8*)&rows[lr][32 + quad * 8];
        short8 b2 = *(const short8*)&rows[lr][64 + quad * 8];
        short8 b3 = *(const short8*)&rows[lr][96 + quad * 8];
        int ncol = wave * 16 + lr;
        const short8* Wp = (const short8*)(Wp1t + (size_t)ncol * 128 + quad * 8);
        short8 a0v = Wp[0], a1v = Wp[4], a2v = Wp[8], a3v = Wp[12];
        floatx4 acc = {0.f, 0.f, 0.f, 0.f};
        acc = __builtin_amdgcn_mfma_f32_16x16x32_bf16(a0v, b0, acc, 0, 0, 0);
        acc = __builtin_amdgcn_mfma_f32_16x16x32_bf16(a1v, b1, acc, 0, 0, 0);
        acc = __builtin_amdgcn_mfma_f32_16x16x32_bf16(a2v, b2, acc, 0, 0, 0);
        acc = __builtin_amdgcn_mfma_f32_16x16x32_bf16(a3v, b3, acc, 0, 0, 0);
        int c0 = wave * 16 + quad * 4;
        float4 bv = *(const float4*)(bp1 + c0);
        uint2 st;
        st.x = f2bf(acc[0] + bv.x) | (f2bf(acc[1] + bv.y) << 16);
        st.y = f2bf(acc[2] + bv.z) | (f2bf(acc[3] + bv.w) << 16);
        *(uint2*)&h1s[lr][c0] = st;
    }
    __syncthreads();
    if (wave < 4) {  // out = sigmoid(h1 @ Wp2 + bp2)
        short8 b0 = *(const short8*)&h1s[lr][quad * 8];
        short8 b1 = *(const short8*)&h1s[lr][32 + quad * 8];
        short8 b2 = *(const short8*)&h1s[lr][64 + quad * 8];
        short8 b3 = *(const short8*)&h1s[lr][96 + quad * 8];
        int ncol = wave * 16 + lr;
        const short8* Wp = (const short8*)(Wp2t + (size_t)ncol * 128 + quad * 8);
        short8 a0v = Wp[0], a1v = Wp[4], a2v = Wp[8], a3v = Wp[12];
        floatx4 acc = {0.f, 0.f, 0.f, 0.f};
        acc = __builtin_amdgcn_mfma_f32_16x16x32_bf16(a0v, b0, acc, 0, 0, 0);
        acc = __builtin_amdgcn_mfma_f32_16x16x32_bf16(a1v, b1, acc, 0, 0, 0);
        acc = __builtin_amdgcn_mfma_f32_16x16x32_bf16(a2v, b2, acc, 0, 0, 0);
        acc = __builtin_amdgcn_mfma_f32_16x16x32_bf16(a3v, b3, acc, 0, 0, 0);
        int c0 = wave * 16 + quad * 4;
        int onode = nb0 + lr;
        if (onode < N) {
            float4 bv = *(const float4*)(bp2 + c0);
            float4 st;
            st.x = 1.f / (1.f + __expf(-(acc[0] + bv.x)));
            st.y = 1.f / (1.f + __expf(-(acc[1] + bv.y)));
            st.z = 1.f / (1.f + __expf(-(acc[2] + bv.z)));
            st.w = 1.f / (1.f + __expf(-(acc[3] + bv.w)));
            *(float4*)(out + (size_t)onode * 64 + c0) = st;
        }
    }
}

extern "C" void kernel_launch(void* const* d_in, const int* in_sizes, int n_in,
                              void* d_out, int out_size, void* d_ws, size_t ws_size,
                              hipStream_t stream) {
    const int N = in_sizes[0] / 128;
    const int E = in_sizes[1] / 2;
    const int nb = (N + 255) >> 8;
    const int* edge = (const int*)d_in[1];
    const int* srcp = edge;
    const int* dstp = edge + E;
    const float* x   = (const float*)d_in[0];
    const float* W1  = (const float*)d_in[2];
    const float* b1  = (const float*)d_in[3];
    const float* W2  = (const float*)d_in[4];
    const float* b2  = (const float*)d_in[5];
    const float* W3  = (const float*)d_in[6];
    const float* b3  = (const float*)d_in[7];
    const float* g1  = (const float*)d_in[8];
    const float* be1 = (const float*)d_in[9];
    const float* g2  = (const float*)d_in[10];
    const float* be2 = (const float*)d_in[11];
    const float* Wp1 = (const float*)d_in[12];
    const float* bp1 = (const float*)d_in[13];
    const float* Wp2 = (const float*)d_in[14];
    const float* bp2 = (const float*)d_in[15];

    char* ws = (char*)d_ws;
    size_t off = 0;
    auto alloc = [&](size_t b) -> char* {
        char* p = ws + off;
        off += (b + 255) & ~(size_t)255;
        return p;
    };
    int* bcnt   = (int*)alloc(512 * 4);
    int* bbase  = (int*)alloc((size_t)(nb + 1) * 4);
    int* cursor = (int*)alloc((size_t)nb * 4);
    int* rowptr = (int*)alloc((size_t)(N + 1) * 4);
    float* dinv = (float*)alloc((size_t)N * 4);
    u32* pairs  = (u32*)alloc((size_t)E * 4);
    int* colA   = (int*)alloc((size_t)E * 4);
    unsigned short* hw  = (unsigned short*)alloc((size_t)N * 128 * 2);
    unsigned short* hb  = (unsigned short*)alloc((size_t)N * 128 * 2);
    unsigned short* w1t = (unsigned short*)alloc(128 * 128 * 2);
    unsigned short* w2t = (unsigned short*)alloc(128 * 128 * 2);
    unsigned short* w3t = (unsigned short*)alloc(128 * 128 * 2);
    unsigned short* wp1t = (unsigned short*)alloc(128 * 128 * 2);
    unsigned short* wp2t = (unsigned short*)alloc(64 * 128 * 2);
    if (off > ws_size) return;

    int gb = (N + 63) / 64;
    int fb = (N + 15) / 16;
    int histB = (E + 4095) / 4096;

    hipMemsetAsync(bcnt, 0, 512 * 4, stream);
    hist_trans_k<<<histB + 288, 256, 0, stream>>>(dstp, bcnt, E, histB,
                                                  W1, W2, W3, Wp1, Wp2,
                                                  w1t, w2t, w3t, wp1t, wp2t);
    bscan_k<<<1, 512, 0, stream>>>(bcnt, bbase, cursor, nb, E);
    bucket_k<<<(E + 8191) / 8192, 256, 0, stream>>>(srcp, dstp, cursor, pairs, E, nb);
    build_k<<<nb, 256, 0, stream>>>(pairs, bbase, rowptr, dinv, colA, N, E);

    // K1: hw = (x@W1)*dinv
    gemm1_k<<<gb, 256, 0, stream>>>(x, (const short*)w1t, dinv, hw, N);
    // K2: hb = (LN(relu(agg(hw)+b1)) @ W2)*dinv
    fconv_k<<<fb, 1024, 0, stream>>>((const u32*)hw, rowptr, colA, dinv, b1, g1, be1,
                                     (const short*)w2t, hb, N);
    // K3: hw = (LN(relu(agg(hb)+b2)) @ W3)*dinv
    fconv_k<<<fb, 1024, 0, stream>>>((const u32*)hb, rowptr, colA, dinv, b2, g2, be2,
                                     (const short*)w3t, hw, N);
    // K4: out = sigmoid((relu(agg(hw)+b3) @ Wp1 + bp1) @ Wp2 + bp2)
    fhead_k<<<fb, 1024, 0, stream>>>((const u32*)hw, rowptr, colA, dinv, b3,
                                     (const short*)wp1t, bp1, (const short*)wp2t, bp2,
                                     (float*)d_out, N);
}